// Round 2
// baseline (1990.397 us; speedup 1.0000x reference)
//
#include <hip/hip_runtime.h>
#include <math.h>

#define N_TOK   131072
#define HID     1024
#define CL      64
#define NEXP    64
#define KC      128     // K-chunk staged in LDS
#define TPW     16      // tokens per wave
#define TPB     64      // tokens per block (4 waves * 16)
#define SWP     68      // padded row stride (floats), 16B-aligned
#define TAU     4e-4f   // near-tie flag threshold (abs distance units)

// ---- workspace layout (bytes) ----
#define WS_CNT   0                       // int
#define WS_LIST  16                      // int[N_TOK]
#define WS_CN    (16 + N_TOK * 4)        // float[NEXP*CL]
#define WS_CN2   (WS_CN + NEXP * CL * 4) // float[NEXP]
#define WS_CND   (WS_CN2 + NEXP * 4)     // double[NEXP*CL]  (offset % 8 == 0)
#define WS_CN2D  (WS_CND + NEXP * CL * 8)// double[NEXP]

__device__ __forceinline__ float wave_sum(float v) {
#pragma unroll
    for (int off = 32; off > 0; off >>= 1) v += __shfl_xor(v, off, 64);
    return v;
}
__device__ __forceinline__ double wave_sum_d(double v) {
#pragma unroll
    for (int off = 32; off > 0; off >>= 1) v += __shfl_xor(v, off, 64);
    return v;
}
__device__ __forceinline__ double wave_max_d(double v) {
#pragma unroll
    for (int off = 32; off > 0; off >>= 1) v = fmax(v, __shfl_xor(v, off, 64));
    return v;
}
// argmax over 64 lanes; ties -> lower index (matches jax.lax.top_k)
__device__ __forceinline__ void wave_argmax(float& v, int& idx) {
#pragma unroll
    for (int off = 32; off > 0; off >>= 1) {
        float v2 = __shfl_xor(v, off, 64);
        int   i2 = __shfl_xor(idx, off, 64);
        if (v2 > v || (v2 == v && i2 < idx)) { v = v2; idx = i2; }
    }
}
__device__ __forceinline__ void wave_argmax_d(double& v, int& idx) {
#pragma unroll
    for (int off = 32; off > 0; off >>= 1) {
        double v2 = __shfl_xor(v, off, 64);
        int    i2 = __shfl_xor(idx, off, 64);
        if (v2 > v || (v2 == v && i2 < idx)) { v = v2; idx = i2; }
    }
}

// Normalize centroids once (f64 master copy + f32 cast), zero flag counter.
extern "C" __global__ void prep_centroids(const float* __restrict__ cent,
                                          float* __restrict__ cn,
                                          float* __restrict__ cn2,
                                          double* __restrict__ cnd,
                                          double* __restrict__ cn2d,
                                          int* __restrict__ cnt) {
    int e = threadIdx.x;  // 64 threads, one expert each
    if (e == 0) *cnt = 0;
    double s = 0.0;
#pragma unroll
    for (int j = 0; j < CL; j++) { double v = (double)cent[e * CL + j]; s += v * v; }
    double nrm = fmax(sqrt(s), 1e-8);
    double s2 = 0.0;
#pragma unroll
    for (int j = 0; j < CL; j++) {
        double c = (double)cent[e * CL + j] / nrm;
        cnd[e * CL + j] = c;
        cn[e * CL + j] = (float)c;
        s2 += c * c;
    }
    cn2d[e] = s2;
    cn2[e] = (float)s2;
}

extern "C" __global__ void __launch_bounds__(256, 2)
router_main(const float* __restrict__ x, const float* __restrict__ W,
            const float* __restrict__ bias, const float* __restrict__ cn,
            const float* __restrict__ cn2, float* __restrict__ out,
            int* __restrict__ cnt, int* __restrict__ list) {
    __shared__ float sW[KC][SWP];       // W chunk, natural [k][j] layout
    __shared__ float sC[NEXP][SWP];     // normalized centroids
    __shared__ float sD[TPB][SWP];      // normalized hidden per token
    __shared__ float sCn2[NEXP];

    const int tid  = threadIdx.x;
    const int lane = tid & 63;
    const int wv   = __builtin_amdgcn_readfirstlane(tid >> 6);  // wave-uniform
    const int tok0 = blockIdx.x * TPB;
    const int twave = tok0 + wv * TPW;

    for (int i = tid; i < NEXP * CL; i += 256) sC[i >> 6][i & 63] = cn[i];
    if (tid < NEXP) sCn2[tid] = cn2[tid];

    float acc[TPW];
#pragma unroll
    for (int i = 0; i < TPW; i++) acc[i] = 0.f;

    for (int kc = 0; kc < HID; kc += KC) {
        __syncthreads();
        for (int s = tid; s < KC * (CL / 4); s += 256) {
            int k = s >> 4, j4 = (s & 15) * 4;
            *(float4*)&sW[k][j4] = *(const float4*)(W + (size_t)(kc + k) * CL + j4);
        }
        __syncthreads();

        const float* xb = x + (size_t)twave * HID + kc;
        for (int k = 0; k < KC; k += 4) {
            float4 xr[TPW];
#pragma unroll
            for (int i = 0; i < TPW; i++)
                xr[i] = *(const float4*)(xb + (size_t)i * HID + k);
            const float w0 = sW[k + 0][lane];
            const float w1 = sW[k + 1][lane];
            const float w2 = sW[k + 2][lane];
            const float w3 = sW[k + 3][lane];
#pragma unroll
            for (int i = 0; i < TPW; i++) {
                acc[i] = fmaf(xr[i].x, w0, acc[i]);
                acc[i] = fmaf(xr[i].y, w1, acc[i]);
                acc[i] = fmaf(xr[i].z, w2, acc[i]);
                acc[i] = fmaf(xr[i].w, w3, acc[i]);
            }
        }
    }

    // epilogue: gelu (exact), l2-normalize across the 64 lanes (= cluster dims)
    const float bj = bias[lane];
    float d2[TPW];
#pragma unroll
    for (int i = 0; i < TPW; i++) {
        float h = acc[i] + bj;
        float g = 0.5f * h * (1.f + erff(h * 0.70710678118654752440f));
        float n2 = wave_sum(g * g);
        float nrm = fmaxf(sqrtf(n2), 1e-8f);
        float d = g / nrm;
        d2[i] = wave_sum(d * d);
        sD[wv * TPW + i][lane] = d;
    }

    // distances: lane = expert; dot(d_token, c_expert) via LDS
    float dot[TPW];
#pragma unroll
    for (int i = 0; i < TPW; i++) dot[i] = 0.f;
    for (int j = 0; j < CL; j += 4) {
        const float4 c4 = *(const float4*)&sC[lane][j];
#pragma unroll
        for (int i = 0; i < TPW; i++) {
            const float4 d4 = *(const float4*)&sD[wv * TPW + i][j];  // broadcast
            float t = fmaf(d4.x, c4.x, fmaf(d4.y, c4.y,
                      fmaf(d4.z, c4.z, fmaf(d4.w, c4.w, 0.f))));
            dot[i] += t;
        }
    }

    const float myCn2 = sCn2[lane];
#pragma unroll 1
    for (int i = 0; i < TPW; i++) {
        float sq   = d2[i] + myCn2 - 2.f * dot[i];
        float dist = sqrtf(fmaxf(sq, 0.f));
        float nd   = -dist;

        // top-3 on negative distance (ordering identical to softmax probs)
        float a1 = nd; int j1 = lane; wave_argmax(a1, j1);
        float nd2m = (lane == j1) ? -1e30f : nd;
        float a2 = nd2m; int j2 = lane; wave_argmax(a2, j2);
        float nd3m = (lane == j2) ? -1e30f : nd2m;
        float a3 = nd3m; int j3 = lane; wave_argmax(a3, j3);

        float e    = expf(nd - a1);
        float ssum = wave_sum(e);
        float p    = e / ssum;
        float p1   = __shfl(p, j1, 64);
        float p2   = __shfl(p, j2, 64);

        bool flag = ((a1 - a2) < TAU) || ((a2 - a3) < TAU);

        if (lane == 0) {
            size_t t = (size_t)(twave + i);
            out[t * 2 + 0] = p1;
            out[t * 2 + 1] = p2;
            out[(size_t)N_TOK * 2 + t * 2 + 0] = (float)j1;
            out[(size_t)N_TOK * 2 + t * 2 + 1] = (float)j2;
            if (flag) { int ix = atomicAdd(cnt, 1); list[ix] = (int)t; }
        }
    }
}

// fp64 rescue for near-tie tokens: 1 wave per token, overwrites its 4 outputs.
extern "C" __global__ void __launch_bounds__(64)
router_rescue(const float* __restrict__ x, const float* __restrict__ W,
              const float* __restrict__ bias, const double* __restrict__ cnd,
              const double* __restrict__ cn2d, const int* __restrict__ list,
              const int* __restrict__ cnt, float* __restrict__ out) {
    __shared__ float  sx[HID];
    __shared__ double sd[CL];
    const int lane = threadIdx.x;
    const int n = *cnt;

    for (int fi = blockIdx.x; fi < n; fi += gridDim.x) {
        __syncthreads();
        const int t = list[fi];
        for (int k = lane; k < HID; k += 64) sx[k] = x[(size_t)t * HID + k];
        __syncthreads();

        // h_lane = sum_k x_k * W[k][lane], f64, 4 partial accumulators
        double h0 = 0.0, h1 = 0.0, h2 = 0.0, h3 = 0.0;
        const float* Wp = W + lane;
        for (int k = 0; k < HID; k += 4) {
            h0 += (double)sx[k + 0] * (double)Wp[(k + 0) * CL];
            h1 += (double)sx[k + 1] * (double)Wp[(k + 1) * CL];
            h2 += (double)sx[k + 2] * (double)Wp[(k + 2) * CL];
            h3 += (double)sx[k + 3] * (double)Wp[(k + 3) * CL];
        }
        double h = (h0 + h1) + (h2 + h3) + (double)bias[lane];
        double g = 0.5 * h * (1.0 + erf(h * 0.70710678118654752440));
        double n2 = wave_sum_d(g * g);
        double nrm = fmax(sqrt(n2), 1e-8);
        double d = g / nrm;
        double d2 = wave_sum_d(d * d);
        sd[lane] = d;
        __syncthreads();

        double dot = 0.0;
        const double* ce = cnd + (size_t)lane * CL;
#pragma unroll 8
        for (int j = 0; j < CL; j++) dot += sd[j] * ce[j];

        double sq   = d2 + cn2d[lane] - 2.0 * dot;
        double dist = sqrt(fmax(sq, 0.0));
        double nd   = -dist;
        double m    = wave_max_d(nd);
        double e    = exp(nd - m);
        double ssum = wave_sum_d(e);
        double p    = e / ssum;

        double a1 = nd; int j1 = lane; wave_argmax_d(a1, j1);
        double ndm = (lane == j1) ? -1e300 : nd;
        double a2 = ndm; int j2 = lane; wave_argmax_d(a2, j2);
        double p1 = __shfl(p, j1, 64);
        double p2 = __shfl(p, j2, 64);

        if (lane == 0) {
            out[(size_t)t * 2 + 0] = (float)p1;
            out[(size_t)t * 2 + 1] = (float)p2;
            out[(size_t)N_TOK * 2 + (size_t)t * 2 + 0] = (float)j1;
            out[(size_t)N_TOK * 2 + (size_t)t * 2 + 1] = (float)j2;
        }
    }
}

extern "C" void kernel_launch(void* const* d_in, const int* in_sizes, int n_in,
                              void* d_out, int out_size, void* d_ws, size_t ws_size,
                              hipStream_t stream) {
    const float* x    = (const float*)d_in[0];
    const float* W    = (const float*)d_in[1];
    const float* bias = (const float*)d_in[2];
    const float* cent = (const float*)d_in[3];
    // k (d_in[4]) == 2, hardcoded

    char* wsb = (char*)d_ws;
    int*    cnt  = (int*)(wsb + WS_CNT);
    int*    list = (int*)(wsb + WS_LIST);
    float*  cn   = (float*)(wsb + WS_CN);
    float*  cn2  = (float*)(wsb + WS_CN2);
    double* cnd  = (double*)(wsb + WS_CND);
    double* cn2d = (double*)(wsb + WS_CN2D);
    float*  out  = (float*)d_out;

    prep_centroids<<<1, 64, 0, stream>>>(cent, cn, cn2, cnd, cn2d, cnt);
    router_main<<<N_TOK / TPB, 256, 0, stream>>>(x, W, bias, cn, cn2, out, cnt, list);
    router_rescue<<<4096, 64, 0, stream>>>(x, W, bias, cnd, cn2d, list, cnt, out);
}